// Round 6
// baseline (297.027 us; speedup 1.0000x reference)
//
#include <hip/hip_runtime.h>
#include <cstdint>

// Problem constants: B=4, S=1024, D=768, H=12, dh=64
#define BB 4
#define SS 1024
#define DD 768
#define HH 12
#define DH 64

typedef unsigned short u16;
typedef unsigned int   u32;
typedef __attribute__((ext_vector_type(8))) short bf16x8;
typedef __attribute__((ext_vector_type(4))) float f32x4;

// fp32 -> bf16 RNE (finite values)
__device__ __forceinline__ u16 f2bf(float f) {
    u32 u = __float_as_uint(f);
    u += 0x7fffu + ((u >> 16) & 1u);
    return (u16)(u >> 16);
}
__device__ __forceinline__ float b2f(u32 lo16) {
    return __uint_as_float(lo16 << 16);
}
__device__ __forceinline__ u32 pack2(float a, float b) {
    return (u32)f2bf(a) | ((u32)f2bf(b) << 16);
}

// async global->LDS, 16 B per lane, LDS dest must be wave-uniform base (+lane*16)
#define ASYNC16(gp, lp) __builtin_amdgcn_global_load_lds( \
    (const __attribute__((address_space(1))) void*)(gp),  \
    (__attribute__((address_space(3))) void*)(lp), 16, 0, 0)

// ---------------- MFMA GEMM body (NT: A[M,K], B[N,K], both K-contiguous bf16) ----
// Tile BM_ x BN_, BK=32, 256 threads = 4 waves in 2x2; wave region (BM_/2)x(BN_/2).
// mfma_f32_16x16x32_bf16; frag layouts per learn_hip m89/m91:
//   A: lane holds A[m=lane&15][k=(lane>>4)*8 + j]
//   B: lane holds Bt[n=lane&15][k=(lane>>4)*8 + j]  (NT rows)
//   C/D: col = lane&15, row = (lane>>4)*4 + reg
template<int BM_, int BN_, class Epi>
__device__ __forceinline__ void mfma_gemm(
    const u16* __restrict__ A, const u16* __restrict__ B,
    int K, int lda, int ldb, int m0, int n0, const Epi& epi)
{
    constexpr int MI = BM_ / 32;   // 16x16 frags per wave along m
    constexpr int NJ = BN_ / 32;
    __shared__ u16 Alds[BM_ * 32];
    __shared__ u16 Blds[BN_ * 32];

    const int tid  = threadIdx.x;
    const int wave = tid >> 6;
    const int lane = tid & 63;
    const int wr = wave >> 1, wc = wave & 1;

    const int ar = lane >> 2;          // staging: row within 16-row group
    const int ac = (lane & 3) * 8;     // staging: col (8 bf16 = 16 B)

    f32x4 acc[MI][NJ] = {};

    for (int k0 = 0; k0 < K; k0 += 32) {
        __syncthreads();               // previous compute done before overwrite
#pragma unroll
        for (int j = 0; j < BM_ / 64; ++j) {
            const int rb = wave * (BM_ / 4) + j * 16;
            ASYNC16(A + (size_t)(m0 + rb + ar) * lda + k0 + ac, &Alds[rb * 32]);
        }
#pragma unroll
        for (int j = 0; j < BN_ / 64; ++j) {
            const int rb = wave * (BN_ / 4) + j * 16;
            ASYNC16(B + (size_t)(n0 + rb + ar) * ldb + k0 + ac, &Blds[rb * 32]);
        }
        __syncthreads();               // drains vmcnt (global_load_lds) + lgkm

        bf16x8 af[MI], bfr[NJ];
#pragma unroll
        for (int mi = 0; mi < MI; ++mi)
            af[mi] = *(const bf16x8*)&Alds[(wr * (BM_ / 2) + mi * 16 + (lane & 15)) * 32 + (lane >> 4) * 8];
#pragma unroll
        for (int nj = 0; nj < NJ; ++nj)
            bfr[nj] = *(const bf16x8*)&Blds[(wc * (BN_ / 2) + nj * 16 + (lane & 15)) * 32 + (lane >> 4) * 8];
#pragma unroll
        for (int mi = 0; mi < MI; ++mi)
#pragma unroll
            for (int nj = 0; nj < NJ; ++nj)
                acc[mi][nj] = __builtin_amdgcn_mfma_f32_16x16x32_bf16(
                    af[mi], bfr[nj], acc[mi][nj], 0, 0, 0);
    }

#pragma unroll
    for (int mi = 0; mi < MI; ++mi)
#pragma unroll
        for (int nj = 0; nj < NJ; ++nj)
#pragma unroll
            for (int r = 0; r < 4; ++r)
                epi(m0 + wr * (BM_ / 2) + mi * 16 + (lane >> 4) * 4 + r,
                    n0 + wc * (BN_ / 2) + nj * 16 + (lane & 15),
                    acc[mi][nj][r]);
}

// ---------------- GEMM kernels ----------------

// qkv = x @ Wqkv^T(t) + bqkv ; scatter into qb (scaled), kb, vt (transposed)
__global__ __launch_bounds__(256) void qkv_gemm_kernel(
    const u16* __restrict__ xb, const u16* __restrict__ Wt,
    const float* __restrict__ bias,
    u16* __restrict__ qb, u16* __restrict__ kb, u16* __restrict__ vt)
{
    struct Epi {
        const float* bias; u16 *qb, *kb, *vt;
        __device__ void operator()(int m, int n, float v) const {
            const float val = v + bias[n];
            const int c = n / DD;                 // block-uniform (768 = 6*128)
            const int w = n - c * DD, h = w >> 6, d = w & 63;
            const int b = m >> 10, s = m & 1023;
            if (c == 0)
                qb[(((size_t)(b * HH + h) << 10) + s) * DH + d] = f2bf(val * 0.125f);
            else if (c == 1)
                kb[(((size_t)(b * HH + h) << 10) + s) * DH + d] = f2bf(val);
            else
                vt[((size_t)(b * HH + h) * DH + d) * SS + s] = f2bf(val);
        }
    } epi{bias, qb, kb, vt};
    mfma_gemm<128, 128>(xb, Wt, DD, DD, DD, blockIdx.y * 128, blockIdx.x * 128, epi);
}

// attn[bhL, q, k] = q . k  (per head-slice; A=qb slice, B=kb slice, K=64)
__global__ __launch_bounds__(256) void qk_gemm_kernel(
    const u16* __restrict__ qb, const u16* __restrict__ kb,
    u16* __restrict__ attn, int bh0)
{
    const int bhL = blockIdx.z;
    const int bh = bh0 + bhL;
    const u16* A = qb + (size_t)bh * SS * DH;
    const u16* B = kb + (size_t)bh * SS * DH;
    u16* C = attn + (size_t)bhL * SS * SS;
    struct Epi {
        u16* C;
        __device__ void operator()(int m, int n, float v) const {
            C[(size_t)m * SS + n] = f2bf(v);
        }
    } epi{C};
    mfma_gemm<128, 128>(A, B, DH, DH, DH, blockIdx.y * 128, blockIdx.x * 128, epi);
}

// ctx[b, q, h*64+d] = attn2[bhL,q,:] . vt[bh,d,:]   (K=1024, N=64)
__global__ __launch_bounds__(256) void pv_gemm_kernel(
    const u16* __restrict__ attn2, const u16* __restrict__ vt,
    u16* __restrict__ ctx, int bh0)
{
    const int bhL = blockIdx.z;
    const int bh = bh0 + bhL;
    const int b = bh / HH, h = bh % HH;
    const u16* A = attn2 + (size_t)bhL * SS * SS;
    const u16* B = vt + (size_t)bh * DH * SS;
    u16* C = ctx + (size_t)b * SS * DD + h * DH;
    struct Epi {
        u16* C;
        __device__ void operator()(int m, int n, float v) const {
            C[(size_t)m * DD + n] = f2bf(v);
        }
    } epi{C};
    mfma_gemm<128, 64>(A, B, SS, SS, SS, blockIdx.y * 128, 0, epi);
}

// out = ctx @ Wproj^T(t) + bproj   (fp32 output)
__global__ __launch_bounds__(256) void proj_gemm_kernel(
    const u16* __restrict__ ctx, const u16* __restrict__ Wt,
    const float* __restrict__ bias, float* __restrict__ out)
{
    struct Epi {
        float* out; const float* bias;
        __device__ void operator()(int m, int n, float v) const {
            out[(size_t)m * DD + n] = v + bias[n];
        }
    } epi{out, bias};
    mfma_gemm<128, 64>(ctx, Wt, DD, DD, DD, blockIdx.y * 128, blockIdx.x * 64, epi);
}

// ---------------- mix + softmax (bf16 in, bf16 out) ----------------
// R6: 2 columns/thread, 512 threads/block. R5's 4-col version needed ~84 live
// VGPRs but the allocator capped at 52 -> serialized loads / remat stalls
// (VALUBusy 88%, dur 3.5x VALU ideal). Halving the per-thread footprint puts
// peak live at ~45 regs: raw[12] u32 (both columns packed in one 4 B load per
// head), e[12][2] accumulator, no psum array (butterfly on e directly).
// __launch_bounds__(512,6) -> 85-reg budget, 6 waves/SIMD.
__global__ __launch_bounds__(512, 6) void mix_softmax_kernel(
    const u16* __restrict__ attn, u16* __restrict__ attn2,
    const float* __restrict__ Wl, const float* __restrict__ bl,
    const float* __restrict__ Ww, const float* __restrict__ bw)
{
    __shared__ float redS[8][HH];
    __shared__ float invS[HH];

    const int tid  = threadIdx.x;
    const int wave = tid >> 6;
    const int lane = tid & 63;
    const int bL = blockIdx.x >> 10;       // local batch within chunk
    const int qi = blockIdx.x & (SS - 1);
    const size_t base = ((size_t)bL * HH * SS + qi) * SS + tid * 2;

    // issue all 12 loads up front (4 B each = 2 bf16 columns, coalesced)
    u32 raw[HH];
#pragma unroll
    for (int h = 0; h < HH; ++h)
        raw[h] = *(const u32*)&attn[base + (size_t)h * SS * SS];

    // mix1, h-outer accumulator form: e[g] = bl[g] + sum_h vin[h]*Wl[h][g]
    float e[HH][2];
#pragma unroll
    for (int g = 0; g < HH; ++g) { e[g][0] = bl[g]; e[g][1] = bl[g]; }
#pragma unroll
    for (int h = 0; h < HH; ++h) {
        const float v0 = b2f(raw[h] & 0xffff);
        const float v1 = b2f(raw[h] >> 16);
#pragma unroll
        for (int g = 0; g < HH; ++g) {
            const float w = Wl[h * HH + g];   // uniform -> s_load
            e[g][0] += v0 * w; e[g][1] += v1 * w;
        }
    }

    // exp in place (no max subtraction: mixed logits are O(2), fp32-safe;
    // softmax is shift-invariant), then butterfly row-sums
#pragma unroll
    for (int g = 0; g < HH; ++g) {
        e[g][0] = __expf(e[g][0]);
        e[g][1] = __expf(e[g][1]);
    }
#pragma unroll
    for (int g = 0; g < HH; ++g) {
        float t = e[g][0] + e[g][1];
#pragma unroll
        for (int off = 32; off; off >>= 1) t += __shfl_xor(t, off);
        if (lane == 0) redS[wave][g] = t;
    }
    __syncthreads();

    // one thread per head finishes the 8-wave sum and inverts
    if (tid < HH) {
        float s = 0.f;
#pragma unroll
        for (int w = 0; w < 8; ++w) s += redS[w][tid];
        invS[tid] = 1.0f / s;
    }
    __syncthreads();

    // fold 1/denominator into e (e == normalized P now)
#pragma unroll
    for (int h = 0; h < HH; ++h) {
        const float inv = invS[h];
        e[h][0] *= inv; e[h][1] *= inv;
    }

    // mix2, g-outer streaming: store each output head immediately
#pragma unroll
    for (int g = 0; g < HH; ++g) {
        const float bg = bw[g];
        float s0 = bg, s1 = bg;
#pragma unroll
        for (int h = 0; h < HH; ++h) {
            const float w = Ww[h * HH + g];   // uniform -> s_load
            s0 += e[h][0] * w; s1 += e[h][1] * w;
        }
        *(u32*)&attn2[base + (size_t)g * SS * SS] = pack2(s0, s1);
    }
}

// ---------------- conversion kernels ----------------

// fp32 -> bf16 elementwise (n multiple of 8)
__global__ __launch_bounds__(256) void cvt_bf16_kernel(
    const float* __restrict__ in, u16* __restrict__ out, int n8)
{
    const int i = blockIdx.x * 256 + threadIdx.x;
    if (i >= n8) return;
    const float4 a = ((const float4*)in)[i * 2];
    const float4 b = ((const float4*)in)[i * 2 + 1];
    uint4 p;
    p.x = pack2(a.x, a.y); p.y = pack2(a.z, a.w);
    p.z = pack2(b.x, b.y); p.w = pack2(b.z, b.w);
    ((uint4*)out)[i] = p;
}

// fp32 [R][C] -> bf16 [C][R] (transpose + convert), 32x32 tiles
__global__ __launch_bounds__(256) void cvt_transpose_kernel(
    const float* __restrict__ in, u16* __restrict__ out, int R, int C)
{
    __shared__ float t[32][33];
    const int c0 = blockIdx.x * 32, r0 = blockIdx.y * 32;
    const int tr = threadIdx.x >> 3;
    const int tc = (threadIdx.x & 7) * 4;
    const float4 v = *(const float4*)&in[(size_t)(r0 + tr) * C + c0 + tc];
    t[tc + 0][tr] = v.x; t[tc + 1][tr] = v.y;
    t[tc + 2][tr] = v.z; t[tc + 3][tr] = v.w;
    __syncthreads();
    uint2 p;
    p.x = pack2(t[tr][tc + 0], t[tr][tc + 1]);
    p.y = pack2(t[tr][tc + 2], t[tr][tc + 3]);
    *(uint2*)&out[(size_t)(c0 + tr) * R + r0 + tc] = p;
}

// ---------------- launch ----------------
extern "C" void kernel_launch(void* const* d_in, const int* in_sizes, int n_in,
                              void* d_out, int out_size, void* d_ws, size_t ws_size,
                              hipStream_t stream)
{
    const float* x     = (const float*)d_in[0];
    const float* Wqkv  = (const float*)d_in[1];
    const float* bqkv  = (const float*)d_in[2];
    const float* Wl    = (const float*)d_in[3];
    const float* bl    = (const float*)d_in[4];
    const float* Ww    = (const float*)d_in[5];
    const float* bw    = (const float*)d_in[6];
    const float* Wproj = (const float*)d_in[7];
    const float* bproj = (const float*)d_in[8];
    float* out = (float*)d_out;

    // workspace (bf16 elems)
    const size_t N_XB  = (size_t)BB * SS * DD;        // 3,145,728
    const size_t N_QB  = (size_t)BB * HH * SS * DH;   // 3,145,728
    const size_t N_WT  = (size_t)DD * 3 * DD;         // 1,769,472
    const size_t N_WP  = (size_t)DD * DD;             //   589,824
    const size_t N_AT1 = (size_t)HH * SS * SS;        // per-batch attn chunk elems

    u16* xb  = (u16*)d_ws;
    u16* qb  = xb  + N_XB;
    u16* kb  = qb  + N_QB;
    u16* vt  = kb  + N_QB;
    u16* ctx = vt  + N_QB;
    u16* Wqkv_t = ctx + N_XB;
    u16* Wproj_t = Wqkv_t + N_WT;
    u16* attn = Wproj_t + N_WP;   // b_per * N_AT1 elems
    // attn2 placed after attn (depends on b_per)

    const size_t fixed_bytes = (size_t)(N_XB * 2 + N_QB * 3 + N_WT + N_WP) * 2;
    int b_per = BB;
    while (b_per > 1 &&
           fixed_bytes + (size_t)b_per * N_AT1 * 2 * 2 > ws_size)
        b_per >>= 1;
    const int n_iter = BB / b_per;
    u16* attn2 = attn + (size_t)b_per * N_AT1;

    const dim3 blk(256);

    // 0) conversions
    cvt_bf16_kernel<<<dim3((N_XB / 8 + 255) / 256), blk, 0, stream>>>(x, xb, (int)(N_XB / 8));
    cvt_transpose_kernel<<<dim3(3 * DD / 32, DD / 32), blk, 0, stream>>>(Wqkv, Wqkv_t, DD, 3 * DD);
    cvt_transpose_kernel<<<dim3(DD / 32, DD / 32), blk, 0, stream>>>(Wproj, Wproj_t, DD, DD);

    // 1) QKV projection (writes qb scaled, kb, vt transposed)
    qkv_gemm_kernel<<<dim3(3 * DD / 128, BB * SS / 128), blk, 0, stream>>>(
        xb, Wqkv_t, bqkv, qb, kb, vt);

    for (int it = 0; it < n_iter; ++it) {
        const int bh0 = it * b_per * HH;
        // 2) logits
        qk_gemm_kernel<<<dim3(SS / 128, SS / 128, b_per * HH), blk, 0, stream>>>(
            qb, kb, attn, bh0);
        // 3) mix1 + softmax + mix2  (512 threads, 2 cols/thread)
        mix_softmax_kernel<<<dim3(b_per * SS), dim3(512), 0, stream>>>(
            attn, attn2, Wl, bl, Ww, bw);
        // 4) PV
        pv_gemm_kernel<<<dim3(1, SS / 128, b_per * HH), blk, 0, stream>>>(
            attn2, vt, ctx, bh0);
    }

    // 5) output projection (fp32 out + bias)
    proj_gemm_kernel<<<dim3(DD / 64, BB * SS / 128), blk, 0, stream>>>(
        ctx, Wproj_t, bproj, out);
}

// Round 7
// 290.469 us; speedup vs baseline: 1.0226x; 1.0226x over previous
//
#include <hip/hip_runtime.h>
#include <cstdint>

// Problem constants: B=4, S=1024, D=768, H=12, dh=64
#define BB 4
#define SS 1024
#define DD 768
#define HH 12
#define DH 64

typedef unsigned short u16;
typedef unsigned int   u32;
typedef __attribute__((ext_vector_type(8))) short bf16x8;
typedef __attribute__((ext_vector_type(4))) float f32x4;

// fp32 -> bf16 RNE (finite values)
__device__ __forceinline__ u16 f2bf(float f) {
    u32 u = __float_as_uint(f);
    u += 0x7fffu + ((u >> 16) & 1u);
    return (u16)(u >> 16);
}
__device__ __forceinline__ float b2f(u32 lo16) {
    return __uint_as_float(lo16 << 16);
}
__device__ __forceinline__ u32 pack2(float a, float b) {
    return (u32)f2bf(a) | ((u32)f2bf(b) << 16);
}

// async global->LDS, 16 B per lane, LDS dest must be wave-uniform base (+lane*16)
#define ASYNC16(gp, lp) __builtin_amdgcn_global_load_lds( \
    (const __attribute__((address_space(1))) void*)(gp),  \
    (__attribute__((address_space(3))) void*)(lp), 16, 0, 0)

// ---------------- MFMA GEMM body (NT: A[M,K], B[N,K], both K-contiguous bf16) ----
// Tile BM_ x BN_, BK=32, 256 threads = 4 waves in 2x2; wave region (BM_/2)x(BN_/2).
// mfma_f32_16x16x32_bf16; frag layouts per learn_hip m89/m91:
//   A: lane holds A[m=lane&15][k=(lane>>4)*8 + j]
//   B: lane holds Bt[n=lane&15][k=(lane>>4)*8 + j]  (NT rows)
//   C/D: col = lane&15, row = (lane>>4)*4 + reg
template<int BM_, int BN_, class Epi>
__device__ __forceinline__ void mfma_gemm(
    const u16* __restrict__ A, const u16* __restrict__ B,
    int K, int lda, int ldb, int m0, int n0, const Epi& epi)
{
    constexpr int MI = BM_ / 32;   // 16x16 frags per wave along m
    constexpr int NJ = BN_ / 32;
    __shared__ u16 Alds[BM_ * 32];
    __shared__ u16 Blds[BN_ * 32];

    const int tid  = threadIdx.x;
    const int wave = tid >> 6;
    const int lane = tid & 63;
    const int wr = wave >> 1, wc = wave & 1;

    const int ar = lane >> 2;          // staging: row within 16-row group
    const int ac = (lane & 3) * 8;     // staging: col (8 bf16 = 16 B)

    f32x4 acc[MI][NJ] = {};

    for (int k0 = 0; k0 < K; k0 += 32) {
        __syncthreads();               // previous compute done before overwrite
#pragma unroll
        for (int j = 0; j < BM_ / 64; ++j) {
            const int rb = wave * (BM_ / 4) + j * 16;
            ASYNC16(A + (size_t)(m0 + rb + ar) * lda + k0 + ac, &Alds[rb * 32]);
        }
#pragma unroll
        for (int j = 0; j < BN_ / 64; ++j) {
            const int rb = wave * (BN_ / 4) + j * 16;
            ASYNC16(B + (size_t)(n0 + rb + ar) * ldb + k0 + ac, &Blds[rb * 32]);
        }
        __syncthreads();               // drains vmcnt (global_load_lds) + lgkm

        bf16x8 af[MI], bfr[NJ];
#pragma unroll
        for (int mi = 0; mi < MI; ++mi)
            af[mi] = *(const bf16x8*)&Alds[(wr * (BM_ / 2) + mi * 16 + (lane & 15)) * 32 + (lane >> 4) * 8];
#pragma unroll
        for (int nj = 0; nj < NJ; ++nj)
            bfr[nj] = *(const bf16x8*)&Blds[(wc * (BN_ / 2) + nj * 16 + (lane & 15)) * 32 + (lane >> 4) * 8];
#pragma unroll
        for (int mi = 0; mi < MI; ++mi)
#pragma unroll
            for (int nj = 0; nj < NJ; ++nj)
                acc[mi][nj] = __builtin_amdgcn_mfma_f32_16x16x32_bf16(
                    af[mi], bfr[nj], acc[mi][nj], 0, 0, 0);
    }

#pragma unroll
    for (int mi = 0; mi < MI; ++mi)
#pragma unroll
        for (int nj = 0; nj < NJ; ++nj)
#pragma unroll
            for (int r = 0; r < 4; ++r)
                epi(m0 + wr * (BM_ / 2) + mi * 16 + (lane >> 4) * 4 + r,
                    n0 + wc * (BN_ / 2) + nj * 16 + (lane & 15),
                    acc[mi][nj][r]);
}

// ---------------- GEMM kernels ----------------

// qkv = x @ Wqkv^T(t) + bqkv ; scatter into qb (scaled), kb, vt (transposed)
__global__ __launch_bounds__(256) void qkv_gemm_kernel(
    const u16* __restrict__ xb, const u16* __restrict__ Wt,
    const float* __restrict__ bias,
    u16* __restrict__ qb, u16* __restrict__ kb, u16* __restrict__ vt)
{
    struct Epi {
        const float* bias; u16 *qb, *kb, *vt;
        __device__ void operator()(int m, int n, float v) const {
            const float val = v + bias[n];
            const int c = n / DD;                 // block-uniform (768 = 6*128)
            const int w = n - c * DD, h = w >> 6, d = w & 63;
            const int b = m >> 10, s = m & 1023;
            if (c == 0)
                qb[(((size_t)(b * HH + h) << 10) + s) * DH + d] = f2bf(val * 0.125f);
            else if (c == 1)
                kb[(((size_t)(b * HH + h) << 10) + s) * DH + d] = f2bf(val);
            else
                vt[((size_t)(b * HH + h) * DH + d) * SS + s] = f2bf(val);
        }
    } epi{bias, qb, kb, vt};
    mfma_gemm<128, 128>(xb, Wt, DD, DD, DD, blockIdx.y * 128, blockIdx.x * 128, epi);
}

// attn[bhL, q, k] = q . k  (per head-slice; A=qb slice, B=kb slice, K=64)
__global__ __launch_bounds__(256) void qk_gemm_kernel(
    const u16* __restrict__ qb, const u16* __restrict__ kb,
    u16* __restrict__ attn, int bh0)
{
    const int bhL = blockIdx.z;
    const int bh = bh0 + bhL;
    const u16* A = qb + (size_t)bh * SS * DH;
    const u16* B = kb + (size_t)bh * SS * DH;
    u16* C = attn + (size_t)bhL * SS * SS;
    struct Epi {
        u16* C;
        __device__ void operator()(int m, int n, float v) const {
            C[(size_t)m * SS + n] = f2bf(v);
        }
    } epi{C};
    mfma_gemm<128, 128>(A, B, DH, DH, DH, blockIdx.y * 128, blockIdx.x * 128, epi);
}

// ctx[b, q, h*64+d] = attn2[bhL,q,:] . vt[bh,d,:]   (K=1024, N=64)
__global__ __launch_bounds__(256) void pv_gemm_kernel(
    const u16* __restrict__ attn2, const u16* __restrict__ vt,
    u16* __restrict__ ctx, int bh0)
{
    const int bhL = blockIdx.z;
    const int bh = bh0 + bhL;
    const int b = bh / HH, h = bh % HH;
    const u16* A = attn2 + (size_t)bhL * SS * SS;
    const u16* B = vt + (size_t)bh * DH * SS;
    u16* C = ctx + (size_t)b * SS * DD + h * DH;
    struct Epi {
        u16* C;
        __device__ void operator()(int m, int n, float v) const {
            C[(size_t)m * DD + n] = f2bf(v);
        }
    } epi{C};
    mfma_gemm<128, 64>(A, B, SS, SS, SS, blockIdx.y * 128, 0, epi);
}

// out = ctx @ Wproj^T(t) + bproj   (fp32 output)
__global__ __launch_bounds__(256) void proj_gemm_kernel(
    const u16* __restrict__ ctx, const u16* __restrict__ Wt,
    const float* __restrict__ bias, float* __restrict__ out)
{
    struct Epi {
        float* out; const float* bias;
        __device__ void operator()(int m, int n, float v) const {
            out[(size_t)m * DD + n] = v + bias[n];
        }
    } epi{out, bias};
    mfma_gemm<128, 64>(ctx, Wt, DD, DD, DD, blockIdx.y * 128, blockIdx.x * 64, epi);
}

// ---------------- mix + softmax (bf16 in, bf16 out) ----------------
// R7: back to the R3 LDS-staging structure (the only variant that performed —
// cooperative staging forces all 12 global loads into flight; register-only
// variants R4-R6 lost to compiler load-sinking + VGPR self-capping at 900-cyc
// HBM latency). Improvements vs R3 (66 us):
//   * bf16 staging: 24 KB LDS (was 48) -> 6 blocks/CU instead of 3
//   * mix2 streams directly to global (no output LDS round-trip)
//   * no max-subtraction in softmax (logits O(2), shift-invariant)
//   * single barrier pair for rowsum combine
__global__ __launch_bounds__(256, 4) void mix_softmax_kernel(
    const u16* __restrict__ attn, u16* __restrict__ attn2,
    const float* __restrict__ Wl, const float* __restrict__ bl,
    const float* __restrict__ Ww, const float* __restrict__ bw)
{
    __shared__ u16 buf[HH][SS];        // 24 KB bf16 staging
    __shared__ float redS[4][HH];
    __shared__ float invS[HH];

    const int tid  = threadIdx.x;
    const int wave = tid >> 6;
    const int lane = tid & 63;
    const int bL = blockIdx.x >> 10;       // local batch within chunk
    const int qi = blockIdx.x & (SS - 1);
    const size_t gbase = ((size_t)bL * HH * SS + qi) * SS + tid * 4;

    // cooperative stage-in: 8 B per head per thread, all loads in flight
#pragma unroll
    for (int h = 0; h < HH; ++h)
        *(uint2*)&buf[h][tid * 4] = *(const uint2*)&attn[gbase + (size_t)h * SS * SS];
    __syncthreads();

    // mix1, h-outer accumulator form, sourced from LDS (low-latency reads)
    float acc[HH][4];
#pragma unroll
    for (int g = 0; g < HH; ++g) {
        const float bg = bl[g];
        acc[g][0] = bg; acc[g][1] = bg; acc[g][2] = bg; acc[g][3] = bg;
    }
#pragma unroll
    for (int h = 0; h < HH; ++h) {
        const uint2 u = *(const uint2*)&buf[h][tid * 4];
        const float v0 = b2f(u.x & 0xffff), v1 = b2f(u.x >> 16);
        const float v2 = b2f(u.y & 0xffff), v3 = b2f(u.y >> 16);
#pragma unroll
        for (int g = 0; g < HH; ++g) {
            const float w = Wl[h * HH + g];   // uniform -> s_load
            acc[g][0] += v0 * w; acc[g][1] += v1 * w;
            acc[g][2] += v2 * w; acc[g][3] += v3 * w;
        }
    }

    // exp in place + butterfly row-sums (no max subtraction)
#pragma unroll
    for (int g = 0; g < HH; ++g) {
        acc[g][0] = __expf(acc[g][0]); acc[g][1] = __expf(acc[g][1]);
        acc[g][2] = __expf(acc[g][2]); acc[g][3] = __expf(acc[g][3]);
        float t = (acc[g][0] + acc[g][1]) + (acc[g][2] + acc[g][3]);
#pragma unroll
        for (int off = 32; off; off >>= 1) t += __shfl_xor(t, off);
        if (lane == 0) redS[wave][g] = t;
    }
    __syncthreads();

    if (tid < HH) {
        invS[tid] = 1.0f / ((redS[0][tid] + redS[1][tid]) +
                            (redS[2][tid] + redS[3][tid]));
    }
    __syncthreads();

    // fold 1/denominator
#pragma unroll
    for (int h = 0; h < HH; ++h) {
        const float inv = invS[h];
        acc[h][0] *= inv; acc[h][1] *= inv;
        acc[h][2] *= inv; acc[h][3] *= inv;
    }

    // mix2, g-outer streaming straight to global
#pragma unroll
    for (int g = 0; g < HH; ++g) {
        const float bg = bw[g];
        float s0 = bg, s1 = bg, s2 = bg, s3 = bg;
#pragma unroll
        for (int h = 0; h < HH; ++h) {
            const float w = Ww[h * HH + g];   // uniform -> s_load
            s0 += acc[h][0] * w; s1 += acc[h][1] * w;
            s2 += acc[h][2] * w; s3 += acc[h][3] * w;
        }
        uint2 p;
        p.x = pack2(s0, s1); p.y = pack2(s2, s3);
        *(uint2*)&attn2[gbase + (size_t)g * SS * SS] = p;
    }
}

// ---------------- conversion kernels ----------------

// fp32 -> bf16 elementwise (n multiple of 8)
__global__ __launch_bounds__(256) void cvt_bf16_kernel(
    const float* __restrict__ in, u16* __restrict__ out, int n8)
{
    const int i = blockIdx.x * 256 + threadIdx.x;
    if (i >= n8) return;
    const float4 a = ((const float4*)in)[i * 2];
    const float4 b = ((const float4*)in)[i * 2 + 1];
    uint4 p;
    p.x = pack2(a.x, a.y); p.y = pack2(a.z, a.w);
    p.z = pack2(b.x, b.y); p.w = pack2(b.z, b.w);
    ((uint4*)out)[i] = p;
}

// fp32 [R][C] -> bf16 [C][R] (transpose + convert), 32x32 tiles
__global__ __launch_bounds__(256) void cvt_transpose_kernel(
    const float* __restrict__ in, u16* __restrict__ out, int R, int C)
{
    __shared__ float t[32][33];
    const int c0 = blockIdx.x * 32, r0 = blockIdx.y * 32;
    const int tr = threadIdx.x >> 3;
    const int tc = (threadIdx.x & 7) * 4;
    const float4 v = *(const float4*)&in[(size_t)(r0 + tr) * C + c0 + tc];
    t[tc + 0][tr] = v.x; t[tc + 1][tr] = v.y;
    t[tc + 2][tr] = v.z; t[tc + 3][tr] = v.w;
    __syncthreads();
    uint2 p;
    p.x = pack2(t[tr][tc + 0], t[tr][tc + 1]);
    p.y = pack2(t[tr][tc + 2], t[tr][tc + 3]);
    *(uint2*)&out[(size_t)(c0 + tr) * R + r0 + tc] = p;
}

// ---------------- launch ----------------
extern "C" void kernel_launch(void* const* d_in, const int* in_sizes, int n_in,
                              void* d_out, int out_size, void* d_ws, size_t ws_size,
                              hipStream_t stream)
{
    const float* x     = (const float*)d_in[0];
    const float* Wqkv  = (const float*)d_in[1];
    const float* bqkv  = (const float*)d_in[2];
    const float* Wl    = (const float*)d_in[3];
    const float* bl    = (const float*)d_in[4];
    const float* Ww    = (const float*)d_in[5];
    const float* bw    = (const float*)d_in[6];
    const float* Wproj = (const float*)d_in[7];
    const float* bproj = (const float*)d_in[8];
    float* out = (float*)d_out;

    // workspace (bf16 elems)
    const size_t N_XB  = (size_t)BB * SS * DD;        // 3,145,728
    const size_t N_QB  = (size_t)BB * HH * SS * DH;   // 3,145,728
    const size_t N_WT  = (size_t)DD * 3 * DD;         // 1,769,472
    const size_t N_WP  = (size_t)DD * DD;             //   589,824
    const size_t N_AT1 = (size_t)HH * SS * SS;        // per-batch attn chunk elems

    u16* xb  = (u16*)d_ws;
    u16* qb  = xb  + N_XB;
    u16* kb  = qb  + N_QB;
    u16* vt  = kb  + N_QB;
    u16* ctx = vt  + N_QB;
    u16* Wqkv_t = ctx + N_XB;
    u16* Wproj_t = Wqkv_t + N_WT;
    u16* attn = Wproj_t + N_WP;   // b_per * N_AT1 elems
    // attn2 placed after attn (depends on b_per)

    const size_t fixed_bytes = (size_t)(N_XB * 2 + N_QB * 3 + N_WT + N_WP) * 2;
    int b_per = BB;
    while (b_per > 1 &&
           fixed_bytes + (size_t)b_per * N_AT1 * 2 * 2 > ws_size)
        b_per >>= 1;
    const int n_iter = BB / b_per;
    u16* attn2 = attn + (size_t)b_per * N_AT1;

    const dim3 blk(256);

    // 0) conversions
    cvt_bf16_kernel<<<dim3((N_XB / 8 + 255) / 256), blk, 0, stream>>>(x, xb, (int)(N_XB / 8));
    cvt_transpose_kernel<<<dim3(3 * DD / 32, DD / 32), blk, 0, stream>>>(Wqkv, Wqkv_t, DD, 3 * DD);
    cvt_transpose_kernel<<<dim3(DD / 32, DD / 32), blk, 0, stream>>>(Wproj, Wproj_t, DD, DD);

    // 1) QKV projection (writes qb scaled, kb, vt transposed)
    qkv_gemm_kernel<<<dim3(3 * DD / 128, BB * SS / 128), blk, 0, stream>>>(
        xb, Wqkv_t, bqkv, qb, kb, vt);

    for (int it = 0; it < n_iter; ++it) {
        const int bh0 = it * b_per * HH;
        // 2) logits
        qk_gemm_kernel<<<dim3(SS / 128, SS / 128, b_per * HH), blk, 0, stream>>>(
            qb, kb, attn, bh0);
        // 3) mix1 + softmax + mix2
        mix_softmax_kernel<<<dim3(b_per * SS), blk, 0, stream>>>(
            attn, attn2, Wl, bl, Ww, bw);
        // 4) PV
        pv_gemm_kernel<<<dim3(1, SS / 128, b_per * HH), blk, 0, stream>>>(
            attn2, vt, ctx, bh0);
    }

    // 5) output projection (fp32 out + bias)
    proj_gemm_kernel<<<dim3(DD / 64, BB * SS / 128), blk, 0, stream>>>(
        ctx, Wproj_t, bproj, out);
}

// Round 8
// 247.487 us; speedup vs baseline: 1.2002x; 1.1737x over previous
//
#include <hip/hip_runtime.h>
#include <cstdint>

// Problem constants: B=4, S=1024, D=768, H=12, dh=64
#define BB 4
#define SS 1024
#define DD 768
#define HH 12
#define DH 64

typedef unsigned short u16;
typedef unsigned int   u32;
typedef __attribute__((ext_vector_type(8))) short bf16x8;
typedef __attribute__((ext_vector_type(4))) float f32x4;

// fp32 -> bf16 RNE (finite values)
__device__ __forceinline__ u16 f2bf(float f) {
    u32 u = __float_as_uint(f);
    u += 0x7fffu + ((u >> 16) & 1u);
    return (u16)(u >> 16);
}
__device__ __forceinline__ float b2f(u32 lo16) {
    return __uint_as_float(lo16 << 16);
}
__device__ __forceinline__ u32 pack2(float a, float b) {
    return (u32)f2bf(a) | ((u32)f2bf(b) << 16);
}

// async global->LDS, 16 B per lane, LDS dest must be wave-uniform base (+lane*16)
#define ASYNC16(gp, lp) __builtin_amdgcn_global_load_lds( \
    (const __attribute__((address_space(1))) void*)(gp),  \
    (__attribute__((address_space(3))) void*)(lp), 16, 0, 0)

// ---------------- MFMA GEMM body (NT: A[M,K], B[N,K], both K-contiguous bf16) ----
// Tile BM_ x BN_, BK=32, 256 threads = 4 waves in 2x2; wave region (BM_/2)x(BN_/2).
// mfma_f32_16x16x32_bf16; frag layouts per learn_hip m89/m91:
//   A: lane holds A[m=lane&15][k=(lane>>4)*8 + j]
//   B: lane holds Bt[n=lane&15][k=(lane>>4)*8 + j]  (NT rows)
//   C/D: col = lane&15, row = (lane>>4)*4 + reg
template<int BM_, int BN_, class Epi>
__device__ __forceinline__ void mfma_gemm(
    const u16* __restrict__ A, const u16* __restrict__ B,
    int K, int lda, int ldb, int m0, int n0, const Epi& epi)
{
    constexpr int MI = BM_ / 32;   // 16x16 frags per wave along m
    constexpr int NJ = BN_ / 32;
    __shared__ u16 Alds[BM_ * 32];
    __shared__ u16 Blds[BN_ * 32];

    const int tid  = threadIdx.x;
    const int wave = tid >> 6;
    const int lane = tid & 63;
    const int wr = wave >> 1, wc = wave & 1;

    const int ar = lane >> 2;          // staging: row within 16-row group
    const int ac = (lane & 3) * 8;     // staging: col (8 bf16 = 16 B)

    f32x4 acc[MI][NJ] = {};

    for (int k0 = 0; k0 < K; k0 += 32) {
        __syncthreads();               // previous compute done before overwrite
#pragma unroll
        for (int j = 0; j < BM_ / 64; ++j) {
            const int rb = wave * (BM_ / 4) + j * 16;
            ASYNC16(A + (size_t)(m0 + rb + ar) * lda + k0 + ac, &Alds[rb * 32]);
        }
#pragma unroll
        for (int j = 0; j < BN_ / 64; ++j) {
            const int rb = wave * (BN_ / 4) + j * 16;
            ASYNC16(B + (size_t)(n0 + rb + ar) * ldb + k0 + ac, &Blds[rb * 32]);
        }
        __syncthreads();               // drains vmcnt (global_load_lds) + lgkm

        bf16x8 af[MI], bfr[NJ];
#pragma unroll
        for (int mi = 0; mi < MI; ++mi)
            af[mi] = *(const bf16x8*)&Alds[(wr * (BM_ / 2) + mi * 16 + (lane & 15)) * 32 + (lane >> 4) * 8];
#pragma unroll
        for (int nj = 0; nj < NJ; ++nj)
            bfr[nj] = *(const bf16x8*)&Blds[(wc * (BN_ / 2) + nj * 16 + (lane & 15)) * 32 + (lane >> 4) * 8];
#pragma unroll
        for (int mi = 0; mi < MI; ++mi)
#pragma unroll
            for (int nj = 0; nj < NJ; ++nj)
                acc[mi][nj] = __builtin_amdgcn_mfma_f32_16x16x32_bf16(
                    af[mi], bfr[nj], acc[mi][nj], 0, 0, 0);
    }

#pragma unroll
    for (int mi = 0; mi < MI; ++mi)
#pragma unroll
        for (int nj = 0; nj < NJ; ++nj)
#pragma unroll
            for (int r = 0; r < 4; ++r)
                epi(m0 + wr * (BM_ / 2) + mi * 16 + (lane >> 4) * 4 + r,
                    n0 + wc * (BN_ / 2) + nj * 16 + (lane & 15),
                    acc[mi][nj][r]);
}

// ---------------- GEMM kernels ----------------

// qkv = x @ Wqkv^T(t) + bqkv ; scatter into qb (scaled), kb, vt (transposed)
__global__ __launch_bounds__(256) void qkv_gemm_kernel(
    const u16* __restrict__ xb, const u16* __restrict__ Wt,
    const float* __restrict__ bias,
    u16* __restrict__ qb, u16* __restrict__ kb, u16* __restrict__ vt)
{
    struct Epi {
        const float* bias; u16 *qb, *kb, *vt;
        __device__ void operator()(int m, int n, float v) const {
            const float val = v + bias[n];
            const int c = n / DD;                 // block-uniform (768 = 6*128)
            const int w = n - c * DD, h = w >> 6, d = w & 63;
            const int b = m >> 10, s = m & 1023;
            if (c == 0)
                qb[(((size_t)(b * HH + h) << 10) + s) * DH + d] = f2bf(val * 0.125f);
            else if (c == 1)
                kb[(((size_t)(b * HH + h) << 10) + s) * DH + d] = f2bf(val);
            else
                vt[((size_t)(b * HH + h) * DH + d) * SS + s] = f2bf(val);
        }
    } epi{bias, qb, kb, vt};
    mfma_gemm<128, 128>(xb, Wt, DD, DD, DD, blockIdx.y * 128, blockIdx.x * 128, epi);
}

// attn[bhL, q, k] = q . k  (per head-slice; A=qb slice, B=kb slice, K=64)
__global__ __launch_bounds__(256) void qk_gemm_kernel(
    const u16* __restrict__ qb, const u16* __restrict__ kb,
    u16* __restrict__ attn, int bh0)
{
    const int bhL = blockIdx.z;
    const int bh = bh0 + bhL;
    const u16* A = qb + (size_t)bh * SS * DH;
    const u16* B = kb + (size_t)bh * SS * DH;
    u16* C = attn + (size_t)bhL * SS * SS;
    struct Epi {
        u16* C;
        __device__ void operator()(int m, int n, float v) const {
            C[(size_t)m * SS + n] = f2bf(v);
        }
    } epi{C};
    mfma_gemm<128, 128>(A, B, DH, DH, DH, blockIdx.y * 128, blockIdx.x * 128, epi);
}

// ctx[b, q, h*64+d] = attn2[bhL,q,:] . vt[bh,d,:]   (K=1024, N=64)
__global__ __launch_bounds__(256) void pv_gemm_kernel(
    const u16* __restrict__ attn2, const u16* __restrict__ vt,
    u16* __restrict__ ctx, int bh0)
{
    const int bhL = blockIdx.z;
    const int bh = bh0 + bhL;
    const int b = bh / HH, h = bh % HH;
    const u16* A = attn2 + (size_t)bhL * SS * SS;
    const u16* B = vt + (size_t)bh * DH * SS;
    u16* C = ctx + (size_t)b * SS * DD + h * DH;
    struct Epi {
        u16* C;
        __device__ void operator()(int m, int n, float v) const {
            C[(size_t)m * DD + n] = f2bf(v);
        }
    } epi{C};
    mfma_gemm<128, 64>(A, B, SS, SS, SS, blockIdx.y * 128, 0, epi);
}

// out = ctx @ Wproj^T(t) + bproj   (fp32 output)
__global__ __launch_bounds__(256) void proj_gemm_kernel(
    const u16* __restrict__ ctx, const u16* __restrict__ Wt,
    const float* __restrict__ bias, float* __restrict__ out)
{
    struct Epi {
        float* out; const float* bias;
        __device__ void operator()(int m, int n, float v) const {
            out[(size_t)m * DD + n] = v + bias[n];
        }
    } epi{out, bias};
    mfma_gemm<128, 64>(ctx, Wt, DD, DD, DD, blockIdx.y * 128, blockIdx.x * 64, epi);
}

// ---------------- mix + softmax (bf16 in, bf16 out) ----------------
// R8: EXACT R3 structure (the only fast variant: phase-local registers, LDS
// round-trips between phases -> allocator never self-caps; R4-R7 all kept a
// 48-float acc live across the kernel and died to remat/serialization).
// Trims vs R3 (66 us):
//   * no max pass (logits O(2), softmax shift-invariant, exp fp32-safe)
//   * mix2 streams straight to global (no output LDS round-trip/stage-out)
//   * no stage-in barrier (stage-in writes and mix1 reads are own-thread
//     columns -> per-thread RAW through LDS, compiler orders via lgkmcnt)
__global__ __launch_bounds__(256) void mix_softmax_kernel(
    const u16* __restrict__ attn, u16* __restrict__ attn2,
    const float* __restrict__ Wl, const float* __restrict__ bl,
    const float* __restrict__ Ww, const float* __restrict__ bw)
{
    __shared__ float buf[HH][SS];          // 48 KB fp32 working buffer
    __shared__ float invden[HH];

    const int tid  = threadIdx.x;
    const int wave = tid >> 6;
    const int lane = tid & 63;
    const int bL = blockIdx.x >> 10;       // local batch within chunk
    const int qi = blockIdx.x & (SS - 1);
    const size_t gbase = ((size_t)bL * HH * SS + qi) * SS + tid * 4;
    const int kc = tid * 4;

    // stage-in: bf16 global -> fp32 LDS, own columns (no barrier needed)
#pragma unroll
    for (int h = 0; h < HH; ++h) {
        const uint2 u = *(const uint2*)&attn[gbase + (size_t)h * SS * SS];
        float4 f;
        f.x = b2f(u.x & 0xffff); f.y = b2f(u.x >> 16);
        f.z = b2f(u.y & 0xffff); f.w = b2f(u.y >> 16);
        *(float4*)&buf[h][kc] = f;
    }

    // mix1: column-local (phase-local vin), write back to LDS
    {
        float4 vin[HH];
#pragma unroll
        for (int h = 0; h < HH; ++h) vin[h] = *(const float4*)&buf[h][kc];
#pragma unroll
        for (int g = 0; g < HH; ++g) {
            float4 s = {bl[g], bl[g], bl[g], bl[g]};
#pragma unroll
            for (int h = 0; h < HH; ++h) {
                const float w = Wl[h * HH + g];   // uniform -> s_load
                s.x += vin[h].x * w; s.y += vin[h].y * w;
                s.z += vin[h].z * w; s.w += vin[h].w * w;
            }
            *(float4*)&buf[g][kc] = s;
        }
    }
    __syncthreads();

    // softmax: wave w handles heads {w, w+4, w+8}; exp (no max) + butterfly
#pragma unroll
    for (int rep = 0; rep < 3; ++rep) {
        const int g = rep * 4 + wave;
        float4 v[4];
#pragma unroll
        for (int j = 0; j < 4; ++j)
            v[j] = *(const float4*)&buf[g][lane * 4 + j * 256];

        float ps = 0.f;
#pragma unroll
        for (int j = 0; j < 4; ++j) {
            v[j].x = __expf(v[j].x); v[j].y = __expf(v[j].y);
            v[j].z = __expf(v[j].z); v[j].w = __expf(v[j].w);
            ps += (v[j].x + v[j].y) + (v[j].z + v[j].w);
        }
#pragma unroll
        for (int off = 32; off; off >>= 1) ps += __shfl_xor(ps, off);

#pragma unroll
        for (int j = 0; j < 4; ++j)
            *(float4*)&buf[g][lane * 4 + j * 256] = v[j];
        if (lane == 0) invden[g] = 1.0f / ps;
    }
    __syncthreads();

    // mix2: column-local with folded 1/l, stream straight to global
    {
        float4 vin[HH];
#pragma unroll
        for (int h = 0; h < HH; ++h) {
            float4 t = *(const float4*)&buf[h][kc];
            const float inv = invden[h];
            t.x *= inv; t.y *= inv; t.z *= inv; t.w *= inv;
            vin[h] = t;
        }
#pragma unroll
        for (int g = 0; g < HH; ++g) {
            float4 s = {bw[g], bw[g], bw[g], bw[g]};
#pragma unroll
            for (int h = 0; h < HH; ++h) {
                const float w = Ww[h * HH + g];   // uniform -> s_load
                s.x += vin[h].x * w; s.y += vin[h].y * w;
                s.z += vin[h].z * w; s.w += vin[h].w * w;
            }
            uint2 p;
            p.x = pack2(s.x, s.y); p.y = pack2(s.z, s.w);
            *(uint2*)&attn2[gbase + (size_t)g * SS * SS] = p;
        }
    }
}

// ---------------- conversion kernels ----------------

// fp32 -> bf16 elementwise (n multiple of 8)
__global__ __launch_bounds__(256) void cvt_bf16_kernel(
    const float* __restrict__ in, u16* __restrict__ out, int n8)
{
    const int i = blockIdx.x * 256 + threadIdx.x;
    if (i >= n8) return;
    const float4 a = ((const float4*)in)[i * 2];
    const float4 b = ((const float4*)in)[i * 2 + 1];
    uint4 p;
    p.x = pack2(a.x, a.y); p.y = pack2(a.z, a.w);
    p.z = pack2(b.x, b.y); p.w = pack2(b.z, b.w);
    ((uint4*)out)[i] = p;
}

// fp32 [R][C] -> bf16 [C][R] (transpose + convert), 32x32 tiles
__global__ __launch_bounds__(256) void cvt_transpose_kernel(
    const float* __restrict__ in, u16* __restrict__ out, int R, int C)
{
    __shared__ float t[32][33];
    const int c0 = blockIdx.x * 32, r0 = blockIdx.y * 32;
    const int tr = threadIdx.x >> 3;
    const int tc = (threadIdx.x & 7) * 4;
    const float4 v = *(const float4*)&in[(size_t)(r0 + tr) * C + c0 + tc];
    t[tc + 0][tr] = v.x; t[tc + 1][tr] = v.y;
    t[tc + 2][tr] = v.z; t[tc + 3][tr] = v.w;
    __syncthreads();
    uint2 p;
    p.x = pack2(t[tr][tc + 0], t[tr][tc + 1]);
    p.y = pack2(t[tr][tc + 2], t[tr][tc + 3]);
    *(uint2*)&out[(size_t)(c0 + tr) * R + r0 + tc] = p;
}

// ---------------- launch ----------------
extern "C" void kernel_launch(void* const* d_in, const int* in_sizes, int n_in,
                              void* d_out, int out_size, void* d_ws, size_t ws_size,
                              hipStream_t stream)
{
    const float* x     = (const float*)d_in[0];
    const float* Wqkv  = (const float*)d_in[1];
    const float* bqkv  = (const float*)d_in[2];
    const float* Wl    = (const float*)d_in[3];
    const float* bl    = (const float*)d_in[4];
    const float* Ww    = (const float*)d_in[5];
    const float* bw    = (const float*)d_in[6];
    const float* Wproj = (const float*)d_in[7];
    const float* bproj = (const float*)d_in[8];
    float* out = (float*)d_out;

    // workspace (bf16 elems)
    const size_t N_XB  = (size_t)BB * SS * DD;        // 3,145,728
    const size_t N_QB  = (size_t)BB * HH * SS * DH;   // 3,145,728
    const size_t N_WT  = (size_t)DD * 3 * DD;         // 1,769,472
    const size_t N_WP  = (size_t)DD * DD;             //   589,824
    const size_t N_AT1 = (size_t)HH * SS * SS;        // per-batch attn chunk elems

    u16* xb  = (u16*)d_ws;
    u16* qb  = xb  + N_XB;
    u16* kb  = qb  + N_QB;
    u16* vt  = kb  + N_QB;
    u16* ctx = vt  + N_QB;
    u16* Wqkv_t = ctx + N_XB;
    u16* Wproj_t = Wqkv_t + N_WT;
    u16* attn = Wproj_t + N_WP;   // b_per * N_AT1 elems
    // attn2 placed after attn (depends on b_per)

    const size_t fixed_bytes = (size_t)(N_XB * 2 + N_QB * 3 + N_WT + N_WP) * 2;
    int b_per = BB;
    while (b_per > 1 &&
           fixed_bytes + (size_t)b_per * N_AT1 * 2 * 2 > ws_size)
        b_per >>= 1;
    const int n_iter = BB / b_per;
    u16* attn2 = attn + (size_t)b_per * N_AT1;

    const dim3 blk(256);

    // 0) conversions
    cvt_bf16_kernel<<<dim3((N_XB / 8 + 255) / 256), blk, 0, stream>>>(x, xb, (int)(N_XB / 8));
    cvt_transpose_kernel<<<dim3(3 * DD / 32, DD / 32), blk, 0, stream>>>(Wqkv, Wqkv_t, DD, 3 * DD);
    cvt_transpose_kernel<<<dim3(DD / 32, DD / 32), blk, 0, stream>>>(Wproj, Wproj_t, DD, DD);

    // 1) QKV projection (writes qb scaled, kb, vt transposed)
    qkv_gemm_kernel<<<dim3(3 * DD / 128, BB * SS / 128), blk, 0, stream>>>(
        xb, Wqkv_t, bqkv, qb, kb, vt);

    for (int it = 0; it < n_iter; ++it) {
        const int bh0 = it * b_per * HH;
        // 2) logits
        qk_gemm_kernel<<<dim3(SS / 128, SS / 128, b_per * HH), blk, 0, stream>>>(
            qb, kb, attn, bh0);
        // 3) mix1 + softmax + mix2
        mix_softmax_kernel<<<dim3(b_per * SS), blk, 0, stream>>>(
            attn, attn2, Wl, bl, Ww, bw);
        // 4) PV
        pv_gemm_kernel<<<dim3(1, SS / 128, b_per * HH), blk, 0, stream>>>(
            attn2, vt, ctx, bh0);
    }

    // 5) output projection (fp32 out + bias)
    proj_gemm_kernel<<<dim3(DD / 64, BB * SS / 128), blk, 0, stream>>>(
        ctx, Wproj_t, bproj, out);
}